// Round 1
// baseline (296.814 us; speedup 1.0000x reference)
//
#include <hip/hip_runtime.h>
#include <hip/hip_bf16.h>

#define NN 8192
#define FIN 128
#define FOUT 64
#define KSPLIT 2
#define BK 64
#define BM 64

typedef __attribute__((ext_vector_type(8))) short short8;
typedef __attribute__((ext_vector_type(4))) float f32x4;

static __device__ __forceinline__ short f2bf(float f) {
    union { __hip_bfloat16 h; short s; } u;
    u.h = __float2bfloat16(f);
    return u.s;
}
static __device__ __forceinline__ float bf2f(short s) {
    union { __hip_bfloat16 h; short s; } u;
    u.s = s;
    return __bfloat162float(u.h);
}

// ---------- XW = X @ W + bias, stored transposed as bf16 hi/lo [FOUT][NN] ----------
__global__ __launch_bounds__(256) void xw_kernel(const float* __restrict__ X,
        const float* __restrict__ W, const float* __restrict__ bias,
        short* __restrict__ XWhi, short* __restrict__ XWlo) {
    __shared__ float Xs[64][FIN + 1];
    const int t = threadIdx.x;
    const int jb = blockIdx.x * 64;
    for (int u = t; u < 64 * FIN; u += 256) {
        int r = u >> 7, k = u & (FIN - 1);
        Xs[r][k] = X[(size_t)(jb + r) * FIN + k];
    }
    __syncthreads();
    const int j = t & 63;
    const int cg = t >> 6;  // wave-uniform column group
    float acc[16];
    #pragma unroll
    for (int q = 0; q < 16; ++q) acc[q] = bias[cg * 16 + q];
    for (int k = 0; k < FIN; ++k) {
        float x = Xs[j][k];
        #pragma unroll
        for (int q = 0; q < 16; ++q)
            acc[q] = fmaf(x, W[k * FOUT + cg * 16 + q], acc[q]);
    }
    #pragma unroll
    for (int q = 0; q < 16; ++q) {
        int c = cg * 16 + q;
        float v = acc[q];
        short hi = f2bf(v);
        float lo = v - bf2f(hi);
        XWhi[(size_t)c * NN + jb + j] = hi;
        XWlo[(size_t)c * NN + jb + j] = f2bf(lo);
    }
}

// ---------- mask(A[,+I]) @ B  with B given transposed [COLS][NN] bf16 hi/lo ----------
// out partial per ks-slice. TOUT: write transposed [ks][COLS][NN], else [ks][NN][COLS].
template <int COLS, bool TOUT, bool DIAG>
__global__ __launch_bounds__(256) void maskmm_kernel(
        const float* __restrict__ A, const short* __restrict__ Bhi,
        const short* __restrict__ Blo, float* __restrict__ outp) {
    constexpr int NT = COLS / 16;
    __shared__ short As[64 * 64];
    __shared__ short Bs[2][COLS * 64];

    const int t = threadIdx.x;
    const int mt = blockIdx.x;
    const int ks = blockIdx.y;
    const int lane = t & 63;
    const int w = t >> 6;

    f32x4 acc[NT];
    #pragma unroll
    for (int n = 0; n < NT; ++n) acc[n] = (f32x4){0.f, 0.f, 0.f, 0.f};

    const int ar = t >> 2;            // staging row 0..63
    const int ach = t & 3;            // 16-float chunk
    const size_t arow = (size_t)(mt * BM + ar) * NN;
    const int grow = mt * BM + ar;

    const int fr = lane & 15;
    const int fg = lane >> 4;
    const int rowA = w * 16 + fr;

    const int kbase = ks * (NN / KSPLIT);

    for (int kt = 0; kt < (NN / KSPLIT) / BK; ++kt) {
        const int k0 = kbase + kt * BK;
        __syncthreads();
        // stage A tile (fp32 -> 0/1 bf16, XOR-swizzled LDS)
        {
            const float4* ap4 = (const float4*)(A + arow + k0 + ach * 16);
            float4 q0 = ap4[0], q1 = ap4[1], q2 = ap4[2], q3 = ap4[3];
            float f[16] = {q0.x, q0.y, q0.z, q0.w, q1.x, q1.y, q1.z, q1.w,
                           q2.x, q2.y, q2.z, q2.w, q3.x, q3.y, q3.z, q3.w};
            union { short s[16]; short8 v[2]; } pk;
            #pragma unroll
            for (int e = 0; e < 16; ++e) {
                bool nz = (f[e] != 0.0f);
                if (DIAG) nz = nz || (grow == (k0 + ach * 16 + e));
                pk.s[e] = nz ? (short)0x3F80 : (short)0;
            }
            const int swz = (ar & 7) << 4;
            int b0 = (ach * 32) ^ swz;
            int b1 = (ach * 32 + 16) ^ swz;
            *(short8*)&As[ar * 64 + (b0 >> 1)] = pk.v[0];
            *(short8*)&As[ar * 64 + (b1 >> 1)] = pk.v[1];
        }
        // stage B tiles (hi & lo), 16B units
        for (int u = t; u < COLS * 8; u += 256) {
            int c = u >> 3, ch = u & 7;
            size_t g = (size_t)c * NN + k0 + ch * 8;
            short8 hv = *(const short8*)(Bhi + g);
            short8 lv = *(const short8*)(Blo + g);
            int bs = (ch * 16) ^ ((c & 7) << 4);
            *(short8*)&Bs[0][c * 64 + (bs >> 1)] = hv;
            *(short8*)&Bs[1][c * 64 + (bs >> 1)] = lv;
        }
        __syncthreads();

        short8 af[2];
        #pragma unroll
        for (int s = 0; s < 2; ++s) {
            int b = (s * 64 + fg * 16) ^ ((rowA & 7) << 4);
            af[s] = *(const short8*)&As[rowA * 64 + (b >> 1)];
        }
        #pragma unroll
        for (int n = 0; n < NT; ++n) {
            const int c = n * 16 + fr;
            const int csw = (c & 7) << 4;
            #pragma unroll
            for (int s = 0; s < 2; ++s) {
                int b = (s * 64 + fg * 16) ^ csw;
                short8 bh = *(const short8*)&Bs[0][c * 64 + (b >> 1)];
                short8 bl = *(const short8*)&Bs[1][c * 64 + (b >> 1)];
                acc[n] = __builtin_amdgcn_mfma_f32_16x16x32_bf16(af[s], bh, acc[n], 0, 0, 0);
                acc[n] = __builtin_amdgcn_mfma_f32_16x16x32_bf16(af[s], bl, acc[n], 0, 0, 0);
            }
        }
    }

    // epilogue: C/D layout col = lane&15, row = (lane>>4)*4 + q
    #pragma unroll
    for (int n = 0; n < NT; ++n) {
        const int c = n * 16 + fr;
        #pragma unroll
        for (int q = 0; q < 4; ++q) {
            const int i = mt * BM + w * 16 + fg * 4 + q;
            if (TOUT)
                outp[((size_t)ks * COLS + c) * NN + i] = acc[n][q];
            else
                outp[((size_t)ks * NN + i) * COLS + c] = acc[n][q];
        }
    }
}

// ---------- sj[i] = sum_c agg[i][c] * phi_j[c] (reduces split-K partials) ----------
__global__ __launch_bounds__(256) void sj_kernel(const float* __restrict__ p0,
        const float* __restrict__ p1, const float* __restrict__ phi,
        float* __restrict__ sjv) {
    int i = blockIdx.x * 256 + threadIdx.x;
    float s = 0.f;
    #pragma unroll
    for (int c = 0; c < FOUT; ++c)
        s += (p0[(size_t)c * NN + i] + p1[(size_t)c * NN + i]) * phi[FOUT + c];
    sjv[i] = s;
}

__global__ __launch_bounds__(256) void max_kernel(const float* __restrict__ sjv,
                                                  float* __restrict__ Mout) {
    __shared__ float red[4];
    float m = -3.0e38f;
    for (int i = threadIdx.x; i < NN; i += 256) m = fmaxf(m, sjv[i]);
    #pragma unroll
    for (int o = 32; o >= 1; o >>= 1) m = fmaxf(m, __shfl_down(m, o, 64));
    if ((threadIdx.x & 63) == 0) red[threadIdx.x >> 6] = m;
    __syncthreads();
    if (threadIdx.x == 0)
        Mout[0] = fmaxf(fmaxf(red[0], red[1]), fmaxf(red[2], red[3]));
}

__global__ __launch_bounds__(256) void ebuild_kernel(const float* __restrict__ sjv,
        const float* __restrict__ Mout, float* __restrict__ e) {
    int i = blockIdx.x * 256 + threadIdx.x;
    e[i] = expf(sjv[i] - Mout[0]);
}

// ---------- B2[c][j]: c<64 -> e_j*agg[j][c]; c==64 -> e_j; 65..79 -> 0 ----------
__global__ __launch_bounds__(256) void bbuild_kernel(const float* __restrict__ p0,
        const float* __restrict__ p1, const float* __restrict__ e,
        short* __restrict__ Bhi, short* __restrict__ Blo) {
    int idx = blockIdx.x * 256 + threadIdx.x;
    int c = idx >> 13;       // / NN
    int j = idx & (NN - 1);
    float x;
    if (c < FOUT)      x = (p0[(size_t)c * NN + j] + p1[(size_t)c * NN + j]) * e[j];
    else if (c == FOUT) x = e[j];
    else               x = 0.f;
    short hi = f2bf(x);
    float lo = x - bf2f(hi);
    Bhi[idx] = hi;
    Blo[idx] = f2bf(lo);
}

// ---------- out = relu(num / den) ----------
__global__ __launch_bounds__(256) void final_kernel(const float* __restrict__ h0,
        const float* __restrict__ h1, float* __restrict__ out) {
    int idx = blockIdx.x * 256 + threadIdx.x;
    int i = idx >> 6, c = idx & 63;
    float num = h0[(size_t)i * 80 + c] + h1[(size_t)i * 80 + c];
    float den = h0[(size_t)i * 80 + 64] + h1[(size_t)i * 80 + 64];
    float v = num / den;
    out[idx] = v > 0.f ? v : 0.f;
}

extern "C" void kernel_launch(void* const* d_in, const int* in_sizes, int n_in,
                              void* d_out, int out_size, void* d_ws, size_t ws_size,
                              hipStream_t stream) {
    const float* A    = (const float*)d_in[0];
    const float* X    = (const float*)d_in[1];
    const float* W    = (const float*)d_in[2];
    const float* bias = (const float*)d_in[3];
    const float* phi  = (const float*)d_in[4];
    float* out = (float*)d_out;

    char* ws = (char*)d_ws;
    size_t off = 0;
    auto alloc = [&](size_t bytes) -> void* {
        void* p = ws + off;
        off += (bytes + 255) & ~(size_t)255;
        return p;
    };
    short* XWhi = (short*)alloc((size_t)FOUT * NN * 2);
    short* XWlo = (short*)alloc((size_t)FOUT * NN * 2);
    float* aggp = (float*)alloc((size_t)KSPLIT * FOUT * NN * 4);
    float* sjv  = (float*)alloc((size_t)NN * 4);
    float* Mb   = (float*)alloc(256);
    float* ev   = (float*)alloc((size_t)NN * 4);
    short* B2hi = (short*)alloc((size_t)80 * NN * 2);
    short* B2lo = (short*)alloc((size_t)80 * NN * 2);
    float* hp   = (float*)alloc((size_t)KSPLIT * NN * 80 * 4);

    const float* p0 = aggp;
    const float* p1 = aggp + (size_t)FOUT * NN;
    const float* h0 = hp;
    const float* h1 = hp + (size_t)NN * 80;

    xw_kernel<<<NN / 64, 256, 0, stream>>>(X, W, bias, XWhi, XWlo);
    maskmm_kernel<64, true, false>
        <<<dim3(NN / BM, KSPLIT), 256, 0, stream>>>(A, XWhi, XWlo, aggp);
    sj_kernel<<<NN / 256, 256, 0, stream>>>(p0, p1, phi, sjv);
    max_kernel<<<1, 256, 0, stream>>>(sjv, Mb);
    ebuild_kernel<<<NN / 256, 256, 0, stream>>>(sjv, Mb, ev);
    bbuild_kernel<<<80 * NN / 256, 256, 0, stream>>>(p0, p1, ev, B2hi, B2lo);
    maskmm_kernel<80, false, true>
        <<<dim3(NN / BM, KSPLIT), 256, 0, stream>>>(A, B2hi, B2lo, hp);
    final_kernel<<<NN * 64 / 256, 256, 0, stream>>>(h0, h1, out);
}

// Round 2
// 226.903 us; speedup vs baseline: 1.3081x; 1.3081x over previous
//
#include <hip/hip_runtime.h>
#include <hip/hip_bf16.h>

#define NN 8192
#define FIN 128
#define FOUT 64
#define KSPLIT 8
#define BK 64
#define BM 64
#define NWORDS (NN / 64)

typedef __attribute__((ext_vector_type(8))) short short8;
typedef __attribute__((ext_vector_type(4))) float f32x4;
typedef unsigned long long u64;

static __device__ __forceinline__ short f2bf(float f) {
    union { __hip_bfloat16 h; short s; } u;
    u.h = __float2bfloat16(f);
    return u.s;
}
static __device__ __forceinline__ float bf2f(short s) {
    union { __hip_bfloat16 h; short s; } u;
    u.s = s;
    return __bfloat162float(u.h);
}

// ---------- A (fp32 0/1, 268MB) -> bitmask (8MB). One wave per row. ----------
__global__ __launch_bounds__(256) void mask_kernel(const float* __restrict__ A,
                                                   u64* __restrict__ mask) {
    const int row = (blockIdx.x * 256 + threadIdx.x) >> 6;
    const int lane = threadIdx.x & 63;
    const size_t rowoff = (size_t)row * NN;
    #pragma unroll 4
    for (int w = 0; w < NWORDS; ++w) {
        float a = A[rowoff + w * 64 + lane];
        u64 b = __ballot(a != 0.0f);
        if (lane == 0) mask[(size_t)row * NWORDS + w] = b;
    }
}

// ---------- XW = X @ W + bias, stored transposed as bf16 hi/lo [FOUT][NN] ----------
__global__ __launch_bounds__(256) void xw_kernel(const float* __restrict__ X,
        const float* __restrict__ W, const float* __restrict__ bias,
        short* __restrict__ XWhi, short* __restrict__ XWlo) {
    __shared__ float Xs[64][FIN + 1];
    const int t = threadIdx.x;
    const int jb = blockIdx.x * 64;
    for (int u = t; u < 64 * FIN; u += 256) {
        int r = u >> 7, k = u & (FIN - 1);
        Xs[r][k] = X[(size_t)(jb + r) * FIN + k];
    }
    __syncthreads();
    const int j = t & 63;
    const int cg = t >> 6;
    float acc[16];
    #pragma unroll
    for (int q = 0; q < 16; ++q) acc[q] = bias[cg * 16 + q];
    for (int k = 0; k < FIN; ++k) {
        float x = Xs[j][k];
        #pragma unroll
        for (int q = 0; q < 16; ++q)
            acc[q] = fmaf(x, W[k * FOUT + cg * 16 + q], acc[q]);
    }
    #pragma unroll
    for (int q = 0; q < 16; ++q) {
        int c = cg * 16 + q;
        float v = acc[q];
        short hi = f2bf(v);
        float lo = v - bf2f(hi);
        XWhi[(size_t)c * NN + jb + j] = hi;
        XWlo[(size_t)c * NN + jb + j] = f2bf(lo);
    }
}

// ---------- mask(A[,+I]) @ B with B transposed [COLS][NN] bf16 hi/lo ----------
template <int COLS, bool TOUT, bool DIAG>
__global__ __launch_bounds__(256) void maskmm_kernel(
        const u64* __restrict__ mask, const short* __restrict__ Bhi,
        const short* __restrict__ Blo, float* __restrict__ outp) {
    constexpr int NT = COLS / 16;
    constexpr int BCH = (COLS * 8 + 255) / 256;
    __shared__ short As[64 * 64];
    __shared__ short Bs[2][COLS * 64];

    const int t = threadIdx.x;
    const int mt = blockIdx.x;
    const int ks = blockIdx.y;
    const int lane = t & 63;
    const int w = t >> 6;

    f32x4 acc[NT];
    #pragma unroll
    for (int n = 0; n < NT; ++n) acc[n] = (f32x4){0.f, 0.f, 0.f, 0.f};

    const int ar = t >> 2;            // staging row 0..63
    const int part = t & 3;           // 16-bit group within row
    const int grow = mt * BM + ar;
    const size_t mrow = (size_t)grow * NWORDS;

    const int fr = lane & 15;
    const int fg = lane >> 4;
    const int rowA = w * 16 + fr;

    const int kbase = ks * (NN / KSPLIT);
    constexpr int KSTEPS = (NN / KSPLIT) / BK;

    for (int kt = 0; kt < KSTEPS; ++kt) {
        const int k0 = kbase + kt * BK;
        // ---- global loads first (overlap previous compute) ----
        u64 mw = mask[mrow + (k0 >> 6)];
        short8 hv[BCH], lv[BCH];
        #pragma unroll
        for (int b = 0; b < BCH; ++b) {
            int u = t + b * 256;
            if (u < COLS * 8) {
                int c = u >> 3, ch = u & 7;
                size_t g = (size_t)c * NN + k0 + ch * 8;
                hv[b] = *(const short8*)(Bhi + g);
                lv[b] = *(const short8*)(Blo + g);
            }
        }
        __syncthreads();  // previous iteration's LDS reads done
        // ---- expand mask bits -> 0/1 bf16, XOR-swizzled LDS ----
        {
            unsigned bits = (unsigned)(mw >> (part * 16)) & 0xFFFFu;
            union { short s[16]; short8 v[2]; } pk;
            #pragma unroll
            for (int e = 0; e < 16; ++e)
                pk.s[e] = ((bits >> e) & 1) ? (short)0x3F80 : (short)0;
            if (DIAG) {
                int d = grow - k0 - part * 16;
                if (d >= 0 && d < 16) pk.s[d] = (short)0x3F80;
            }
            const int swz = (ar & 7) << 4;
            int b0 = (part * 32) ^ swz;
            int b1 = (part * 32 + 16) ^ swz;
            *(short8*)&As[ar * 64 + (b0 >> 1)] = pk.v[0];
            *(short8*)&As[ar * 64 + (b1 >> 1)] = pk.v[1];
        }
        // ---- store B tiles ----
        #pragma unroll
        for (int b = 0; b < BCH; ++b) {
            int u = t + b * 256;
            if (u < COLS * 8) {
                int c = u >> 3, ch = u & 7;
                int bs = (ch * 16) ^ ((c & 7) << 4);
                *(short8*)&Bs[0][c * 64 + (bs >> 1)] = hv[b];
                *(short8*)&Bs[1][c * 64 + (bs >> 1)] = lv[b];
            }
        }
        __syncthreads();

        short8 af[2];
        #pragma unroll
        for (int s = 0; s < 2; ++s) {
            int b = (s * 64 + fg * 16) ^ ((rowA & 7) << 4);
            af[s] = *(const short8*)&As[rowA * 64 + (b >> 1)];
        }
        #pragma unroll
        for (int n = 0; n < NT; ++n) {
            const int c = n * 16 + fr;
            const int csw = (c & 7) << 4;
            #pragma unroll
            for (int s = 0; s < 2; ++s) {
                int b = (s * 64 + fg * 16) ^ csw;
                short8 bh = *(const short8*)&Bs[0][c * 64 + (b >> 1)];
                short8 bl = *(const short8*)&Bs[1][c * 64 + (b >> 1)];
                acc[n] = __builtin_amdgcn_mfma_f32_16x16x32_bf16(af[s], bh, acc[n], 0, 0, 0);
                acc[n] = __builtin_amdgcn_mfma_f32_16x16x32_bf16(af[s], bl, acc[n], 0, 0, 0);
            }
        }
    }

    #pragma unroll
    for (int n = 0; n < NT; ++n) {
        const int c = n * 16 + fr;
        #pragma unroll
        for (int q = 0; q < 4; ++q) {
            const int i = mt * BM + w * 16 + fg * 4 + q;
            if (TOUT)
                outp[((size_t)ks * COLS + c) * NN + i] = acc[n][q];
            else
                outp[((size_t)ks * NN + i) * COLS + c] = acc[n][q];
        }
    }
}

// ---------- reduce 8 split-K partials -> aggr [FOUT][NN] ----------
__global__ __launch_bounds__(256) void reduce_kernel(const float* __restrict__ aggp,
                                                     float* __restrict__ aggr) {
    size_t idx = (size_t)blockIdx.x * 256 + threadIdx.x;
    float v = 0.f;
    #pragma unroll
    for (int ks = 0; ks < KSPLIT; ++ks) v += aggp[(size_t)ks * FOUT * NN + idx];
    aggr[idx] = v;
}

// ---------- sj[i] = sum_c aggr[c][i] * phi_j[c] ----------
__global__ __launch_bounds__(256) void sj_kernel(const float* __restrict__ aggr,
        const float* __restrict__ phi, float* __restrict__ sjv) {
    int i = blockIdx.x * 256 + threadIdx.x;
    float s = 0.f;
    #pragma unroll
    for (int c = 0; c < FOUT; ++c)
        s += aggr[(size_t)c * NN + i] * phi[FOUT + c];
    sjv[i] = s;
}

__global__ __launch_bounds__(256) void max_kernel(const float* __restrict__ sjv,
                                                  float* __restrict__ Mout) {
    __shared__ float red[4];
    float m = -3.0e38f;
    for (int i = threadIdx.x; i < NN; i += 256) m = fmaxf(m, sjv[i]);
    #pragma unroll
    for (int o = 32; o >= 1; o >>= 1) m = fmaxf(m, __shfl_down(m, o, 64));
    if ((threadIdx.x & 63) == 0) red[threadIdx.x >> 6] = m;
    __syncthreads();
    if (threadIdx.x == 0)
        Mout[0] = fmaxf(fmaxf(red[0], red[1]), fmaxf(red[2], red[3]));
}

__global__ __launch_bounds__(256) void ebuild_kernel(const float* __restrict__ sjv,
        const float* __restrict__ Mout, float* __restrict__ e) {
    int i = blockIdx.x * 256 + threadIdx.x;
    e[i] = expf(sjv[i] - Mout[0]);
}

// ---------- B2[c][j]: c<64 -> e_j*aggr[c][j]; c==64 -> e_j; 65..79 -> 0 ----------
__global__ __launch_bounds__(256) void bbuild_kernel(const float* __restrict__ aggr,
        const float* __restrict__ e, short* __restrict__ Bhi, short* __restrict__ Blo) {
    int idx = blockIdx.x * 256 + threadIdx.x;
    int c = idx >> 13;
    int j = idx & (NN - 1);
    float x;
    if (c < FOUT)       x = aggr[(size_t)c * NN + j] * e[j];
    else if (c == FOUT) x = e[j];
    else                x = 0.f;
    short hi = f2bf(x);
    float lo = x - bf2f(hi);
    Bhi[idx] = hi;
    Blo[idx] = f2bf(lo);
}

// ---------- out = relu(num / den), reducing 8 partials ----------
__global__ __launch_bounds__(256) void final_kernel(const float* __restrict__ hp,
                                                    float* __restrict__ out) {
    int idx = blockIdx.x * 256 + threadIdx.x;
    int i = idx >> 6, c = idx & 63;
    float num = 0.f, den = 0.f;
    #pragma unroll
    for (int ks = 0; ks < KSPLIT; ++ks) {
        num += hp[((size_t)ks * NN + i) * 80 + c];
        den += hp[((size_t)ks * NN + i) * 80 + 64];
    }
    float v = num / den;
    out[idx] = v > 0.f ? v : 0.f;
}

extern "C" void kernel_launch(void* const* d_in, const int* in_sizes, int n_in,
                              void* d_out, int out_size, void* d_ws, size_t ws_size,
                              hipStream_t stream) {
    const float* A    = (const float*)d_in[0];
    const float* X    = (const float*)d_in[1];
    const float* W    = (const float*)d_in[2];
    const float* bias = (const float*)d_in[3];
    const float* phi  = (const float*)d_in[4];
    float* out = (float*)d_out;

    char* ws = (char*)d_ws;
    size_t off = 0;
    auto alloc = [&](size_t bytes) -> void* {
        void* p = ws + off;
        off += (bytes + 255) & ~(size_t)255;
        return p;
    };
    u64*   maskb = (u64*)alloc((size_t)NN * NWORDS * 8);
    short* XWhi = (short*)alloc((size_t)FOUT * NN * 2);
    short* XWlo = (short*)alloc((size_t)FOUT * NN * 2);
    float* aggp = (float*)alloc((size_t)KSPLIT * FOUT * NN * 4);
    float* aggr = (float*)alloc((size_t)FOUT * NN * 4);
    float* sjv  = (float*)alloc((size_t)NN * 4);
    float* Mb   = (float*)alloc(256);
    float* ev   = (float*)alloc((size_t)NN * 4);
    short* B2hi = (short*)alloc((size_t)80 * NN * 2);
    short* B2lo = (short*)alloc((size_t)80 * NN * 2);
    float* hp   = (float*)alloc((size_t)KSPLIT * NN * 80 * 4);

    mask_kernel<<<NN / 4, 256, 0, stream>>>(A, maskb);
    xw_kernel<<<NN / 64, 256, 0, stream>>>(X, W, bias, XWhi, XWlo);
    maskmm_kernel<64, true, false>
        <<<dim3(NN / BM, KSPLIT), 256, 0, stream>>>(maskb, XWhi, XWlo, aggp);
    reduce_kernel<<<FOUT * NN / 256, 256, 0, stream>>>(aggp, aggr);
    sj_kernel<<<NN / 256, 256, 0, stream>>>(aggr, phi, sjv);
    max_kernel<<<1, 256, 0, stream>>>(sjv, Mb);
    ebuild_kernel<<<NN / 256, 256, 0, stream>>>(sjv, Mb, ev);
    bbuild_kernel<<<80 * NN / 256, 256, 0, stream>>>(aggr, ev, B2hi, B2lo);
    maskmm_kernel<80, false, true>
        <<<dim3(NN / BM, KSPLIT), 256, 0, stream>>>(maskb, B2hi, B2lo, hp);
    final_kernel<<<NN * 64 / 256, 256, 0, stream>>>(hp, out);
}